// Round 1
// baseline (1327.063 us; speedup 1.0000x reference)
//
#include <hip/hip_runtime.h>
#include <math.h>

// Problem constants
#define Bq 2
#define Lq 1024
#define DM 768
#define DI 1536
#define DS 16
#define DTR 48
#define DC 4
#define BL 2048          // B*L rows
#define NCH 32           // scan chunks
#define CLEN 32          // chunk length (NCH*CLEN == Lq)

// ---------------------------------------------------------------------------
// LayerNorm: one block per row of D elements
// ---------------------------------------------------------------------------
__global__ __launch_bounds__(256) void ln_kernel(const float* __restrict__ x,
                                                 const float* __restrict__ w,
                                                 const float* __restrict__ b,
                                                 float* __restrict__ out, int D) {
  int row = blockIdx.x;
  const float* xr = x + (size_t)row * D;
  float s = 0.f, s2 = 0.f;
  for (int i = threadIdx.x; i < D; i += 256) {
    float v = xr[i];
    s += v; s2 += v * v;
  }
  #pragma unroll
  for (int off = 32; off > 0; off >>= 1) {
    s  += __shfl_down(s, off);
    s2 += __shfl_down(s2, off);
  }
  __shared__ float ss[4], ss2[4];
  int wid = threadIdx.x >> 6;
  if ((threadIdx.x & 63) == 0) { ss[wid] = s; ss2[wid] = s2; }
  __syncthreads();
  if (threadIdx.x == 0) {
    float a = 0.f, a2 = 0.f;
    #pragma unroll
    for (int i = 0; i < 4; i++) { a += ss[i]; a2 += ss2[i]; }
    ss[0] = a; ss2[0] = a2;
  }
  __syncthreads();
  float mu  = ss[0] / D;
  float var = ss2[0] / D - mu * mu;
  float inv = rsqrtf(var + 1e-5f);
  for (int i = threadIdx.x; i < D; i += 256)
    out[(size_t)row * D + i] = (xr[i] - mu) * inv * w[i] + b[i];
}

// ---------------------------------------------------------------------------
// Generic fp32 NT GEMM:  C[M,N] = act( A'[M,K] @ W[N,K]^T + bias ) (+resid)
//   A' row r = A[rowflip(r)] if flipA (flip within each L-batch)
//   cmode 0: C[r] = v    cmode 1: C[flip(r)] += v
//   act 0 none, 1 softplus, 2 gelu(exact)
// Tile 64x64x16, 256 threads, 4x4 per thread.
// ---------------------------------------------------------------------------
__global__ __launch_bounds__(256) void gemm_nt(
    const float* __restrict__ A, int lda,
    const float* __restrict__ W,
    const float* __restrict__ bias,
    const float* __restrict__ resid,
    float* __restrict__ C,
    int M, int N, int K,
    int flipA, int cmode, int act) {
  __shared__ float As[16][68];
  __shared__ float Ws[16][68];
  int t  = threadIdx.x;
  int tx = t & 15, ty = t >> 4;
  int n0 = blockIdx.x * 64;
  int m0 = blockIdx.y * 64;
  int lk = t & 15;   // k within tile for staging
  int lm = t >> 4;   // row group for staging

  float acc[4][4] = {};

  for (int k0 = 0; k0 < K; k0 += 16) {
    #pragma unroll
    for (int i = 0; i < 4; i++) {
      int m = lm + i * 16;
      int r = m0 + m;
      int rr = r;
      if (flipA) { int bb = r >> 10; int l = r & 1023; rr = (bb << 10) + (1023 - l); }
      As[lk][m] = A[(size_t)rr * lda + k0 + lk];
    }
    #pragma unroll
    for (int i = 0; i < 4; i++) {
      int n = lm + i * 16;
      int gn = n0 + n;
      Ws[lk][n] = (gn < N) ? W[(size_t)gn * K + k0 + lk] : 0.f;
    }
    __syncthreads();
    #pragma unroll
    for (int kk = 0; kk < 16; kk++) {
      float a[4], wv[4];
      #pragma unroll
      for (int i = 0; i < 4; i++) a[i] = As[kk][ty * 4 + i];
      #pragma unroll
      for (int j = 0; j < 4; j++) wv[j] = Ws[kk][tx * 4 + j];
      #pragma unroll
      for (int i = 0; i < 4; i++)
        #pragma unroll
        for (int j = 0; j < 4; j++)
          acc[i][j] = fmaf(a[i], wv[j], acc[i][j]);
    }
    __syncthreads();
  }

  #pragma unroll
  for (int i = 0; i < 4; i++) {
    int r = m0 + ty * 4 + i;
    int rout = r;
    if (cmode == 1) { int bb = r >> 10; int l = r & 1023; rout = (bb << 10) + (1023 - l); }
    #pragma unroll
    for (int j = 0; j < 4; j++) {
      int c = n0 + tx * 4 + j;
      if (c >= N) continue;
      float v = acc[i][j];
      if (bias) v += bias[c];
      if (act == 1) {                       // softplus
        v = (v > 20.f) ? v : log1pf(expf(v));
      } else if (act == 2) {                // exact gelu
        v = 0.5f * v * (1.f + erff(v * 0.70710678118654752f));
      }
      if (resid) v += resid[(size_t)r * N + c];
      size_t ci = (size_t)rout * N + c;
      if (cmode == 1) C[ci] += v; else C[ci] = v;
    }
  }
}

// ---------------------------------------------------------------------------
// Causal depthwise conv (k=4) + bias + silu.  xz is [BL,2*DI]; uses first half.
// ---------------------------------------------------------------------------
__global__ __launch_bounds__(256) void conv_silu(const float* __restrict__ xz,
                                                 const float* __restrict__ cw,
                                                 const float* __restrict__ cb,
                                                 float* __restrict__ out) {
  int g = blockIdx.x * 256 + threadIdx.x;          // BL*DI total
  int d = g % DI;
  int r = g / DI;
  int b = r >> 10, l = r & 1023;
  float v = cb[d];
  #pragma unroll
  for (int k = 0; k < DC; k++) {
    int li = l - (DC - 1) + k;
    if (li >= 0)
      v = fmaf(xz[((size_t)((b << 10) + li)) * (2 * DI) + d], cw[d * DC + k], v);
  }
  float s = v / (1.f + __expf(-v));                // silu
  out[(size_t)r * DI + d] = s;
}

// ---------------------------------------------------------------------------
// Scan pass A: per (b,d,chunk) local scan with h0=0.
// P[n] = prod dA over chunk, S[n] = h at chunk end.
// Layout of P/S/H: [b][d][chunk][16]
// ---------------------------------------------------------------------------
__global__ __launch_bounds__(256) void scan_passA(const float* __restrict__ dt,
                                                  const float* __restrict__ xcc,
                                                  const float* __restrict__ xdbl,
                                                  const float* __restrict__ A_log,
                                                  float* __restrict__ P,
                                                  float* __restrict__ S) {
  int g = blockIdx.x * 256 + threadIdx.x;          // Bq*DI*NCH
  int d = g % DI;
  int rest = g / DI;
  int c = rest % NCH;
  int b = rest / NCH;
  float Av[DS], h[DS], Pr[DS];
  #pragma unroll
  for (int n = 0; n < DS; n++) {
    Av[n] = -expf(A_log[d * DS + n]);
    h[n] = 0.f; Pr[n] = 1.f;
  }
  for (int t = 0; t < CLEN; t++) {
    int l = c * CLEN + t;
    int r = (b << 10) + l;
    float dtv = dt[(size_t)r * DI + d];
    float xcv = xcc[(size_t)r * DI + d];
    float dx = dtv * xcv;
    const float* Bp = xdbl + (size_t)r * 80 + DTR;
    #pragma unroll
    for (int n = 0; n < DS; n++) {
      float dA = __expf(dtv * Av[n]);
      h[n] = fmaf(dA, h[n], dx * Bp[n]);
      Pr[n] *= dA;
    }
  }
  size_t base = (((size_t)(b * DI + d)) * NCH + c) * DS;
  #pragma unroll
  for (int n = 0; n < DS; n++) { P[base + n] = Pr[n]; S[base + n] = h[n]; }
}

// ---------------------------------------------------------------------------
// Scan pass B: sequential scan over chunks; H[c] = carry INTO chunk c.
// ---------------------------------------------------------------------------
__global__ __launch_bounds__(256) void scan_passB(const float* __restrict__ P,
                                                  const float* __restrict__ S,
                                                  float* __restrict__ H) {
  int g = blockIdx.x * 256 + threadIdx.x;          // Bq*DI*DS
  int n = g & (DS - 1);
  int d = (g >> 4) % DI;
  int b = g / (DS * DI);
  size_t base = ((size_t)(b * DI + d)) * NCH * DS + n;
  float h = 0.f;
  for (int c = 0; c < NCH; c++) {
    size_t idx = base + (size_t)c * DS;
    H[idx] = h;
    h = fmaf(P[idx], h, S[idx]);
  }
}

// ---------------------------------------------------------------------------
// Scan pass C: replay chunk with carry-in; emit yact = (y + xc*D) * silu(z)
// ---------------------------------------------------------------------------
__global__ __launch_bounds__(256) void scan_passC(const float* __restrict__ dt,
                                                  const float* __restrict__ xcc,
                                                  const float* __restrict__ xdbl,
                                                  const float* __restrict__ A_log,
                                                  const float* __restrict__ H,
                                                  const float* __restrict__ Dvec,
                                                  const float* __restrict__ xz,
                                                  float* __restrict__ yact) {
  int g = blockIdx.x * 256 + threadIdx.x;
  int d = g % DI;
  int rest = g / DI;
  int c = rest % NCH;
  int b = rest / NCH;
  float Av[DS], h[DS];
  size_t base = (((size_t)(b * DI + d)) * NCH + c) * DS;
  #pragma unroll
  for (int n = 0; n < DS; n++) {
    Av[n] = -expf(A_log[d * DS + n]);
    h[n] = H[base + n];
  }
  float Dd = Dvec[d];
  for (int t = 0; t < CLEN; t++) {
    int l = c * CLEN + t;
    int r = (b << 10) + l;
    float dtv = dt[(size_t)r * DI + d];
    float xcv = xcc[(size_t)r * DI + d];
    float dx = dtv * xcv;
    const float* Bp = xdbl + (size_t)r * 80 + DTR;
    const float* Cp = xdbl + (size_t)r * 80 + DTR + DS;
    float y = 0.f;
    #pragma unroll
    for (int n = 0; n < DS; n++) {
      float dA = __expf(dtv * Av[n]);
      h[n] = fmaf(dA, h[n], dx * Bp[n]);
      y = fmaf(h[n], Cp[n], y);
    }
    float z = xz[(size_t)r * (2 * DI) + DI + d];
    float sz = z / (1.f + __expf(-z));
    yact[(size_t)r * DI + d] = (y + xcv * Dd) * sz;
  }
}

// ---------------------------------------------------------------------------
// x2 += x (residual)
// ---------------------------------------------------------------------------
__global__ __launch_bounds__(256) void add_x(float* __restrict__ x2,
                                             const float* __restrict__ x) {
  int g = blockIdx.x * 256 + threadIdx.x;
  x2[g] += x[g];
}

// ---------------------------------------------------------------------------
extern "C" void kernel_launch(void* const* d_in, const int* in_sizes, int n_in,
                              void* d_out, int out_size, void* d_ws, size_t ws_size,
                              hipStream_t stream) {
  const float* x     = (const float*)d_in[0];
  const float* ln1_w = (const float*)d_in[1];
  const float* ln1_b = (const float*)d_in[2];
  const float* ln2_w = (const float*)d_in[3];
  const float* ln2_b = (const float*)d_in[4];
  const float* fc_w  = (const float*)d_in[5];
  const float* fc_b  = (const float*)d_in[6];

  float* ws = (float*)d_ws;
  float* xn   = ws;                 // 1,572,864
  float* xz   = xn   + 1572864;     // 6,291,456
  float* xcc  = xz   + 6291456;     // 3,145,728
  float* xdbl = xcc  + 3145728;     //   163,840
  float* dtb  = xdbl + 163840;      // 3,145,728
  float* Pb   = dtb  + 3145728;     // 1,572,864
  float* Sb   = Pb   + 1572864;     // 1,572,864
  float* Hb   = Sb   + 1572864;     // 1,572,864
  float* yact = Hb   + 1572864;     // 3,145,728
  float* x2   = yact + 3145728;     // 1,572,864
  float* xh   = Pb;                 // alias: P dead after last passB

  ln_kernel<<<BL, 256, 0, stream>>>(x, ln1_w, ln1_b, xn, DM);

  for (int dir = 0; dir < 2; dir++) {
    int pi = 7 + dir * 9;
    const float* in_proj_w  = (const float*)d_in[pi + 0];
    const float* conv_w     = (const float*)d_in[pi + 1];
    const float* conv_b     = (const float*)d_in[pi + 2];
    const float* x_proj_w   = (const float*)d_in[pi + 3];
    const float* dt_proj_w  = (const float*)d_in[pi + 4];
    const float* dt_proj_b  = (const float*)d_in[pi + 5];
    const float* A_log      = (const float*)d_in[pi + 6];
    const float* Dvec       = (const float*)d_in[pi + 7];
    const float* out_proj_w = (const float*)d_in[pi + 8];

    // xz = xn(_flipped) @ in_proj_w.T        [2048 x 3072]
    gemm_nt<<<dim3(48, 32), 256, 0, stream>>>(xn, DM, in_proj_w, nullptr, nullptr,
                                              xz, BL, 2 * DI, DM, dir, 0, 0);
    // depthwise causal conv + silu           [2048 x 1536]
    conv_silu<<<(BL * DI) / 256, 256, 0, stream>>>(xz, conv_w, conv_b, xcc);
    // x_dbl = xcc @ x_proj_w.T               [2048 x 80]
    gemm_nt<<<dim3(2, 32), 256, 0, stream>>>(xcc, DI, x_proj_w, nullptr, nullptr,
                                             xdbl, BL, 80, DI, 0, 0, 0);
    // dt = softplus(x_dbl[:, :48] @ dt_proj_w.T + dt_proj_b)   [2048 x 1536]
    gemm_nt<<<dim3(24, 32), 256, 0, stream>>>(xdbl, 80, dt_proj_w, dt_proj_b, nullptr,
                                              dtb, BL, DI, DTR, 0, 0, 1);
    // chunked selective scan
    scan_passA<<<(Bq * DI * NCH) / 256, 256, 0, stream>>>(dtb, xcc, xdbl, A_log, Pb, Sb);
    scan_passB<<<(Bq * DI * DS) / 256, 256, 0, stream>>>(Pb, Sb, Hb);
    scan_passC<<<(Bq * DI * NCH) / 256, 256, 0, stream>>>(dtb, xcc, xdbl, A_log, Hb,
                                                          Dvec, xz, yact);
    // out_proj; dir 0: store, dir 1: flip-accumulate
    gemm_nt<<<dim3(12, 32), 256, 0, stream>>>(yact, DI, out_proj_w, nullptr, nullptr,
                                              x2, BL, DM, DI, 0, dir, 0);
  }

  // x2 = x + y_total
  add_x<<<(BL * DM) / 256, 256, 0, stream>>>(x2, x);
  // xh = layernorm(x2)
  ln_kernel<<<BL, 256, 0, stream>>>(x2, ln2_w, ln2_b, xh, DM);
  // out = gelu(xh @ fc_w.T + fc_b) + x2
  gemm_nt<<<dim3(12, 32), 256, 0, stream>>>(xh, DM, fc_w, fc_b, x2,
                                            (float*)d_out, BL, DM, DM, 0, 0, 2);
}

// Round 2
// 507.602 us; speedup vs baseline: 2.6144x; 2.6144x over previous
//
#include <hip/hip_runtime.h>
#include <math.h>

// Problem constants
#define Bq 2
#define Lq 1024
#define DM 768
#define DI 1536
#define DS 16
#define DTR 48
#define DC 4
#define BL 2048          // B*L rows
#define NCH 32           // scan chunks
#define CLEN 32          // chunk length (NCH*CLEN == Lq)

typedef __bf16 bf16_t;
typedef __attribute__((ext_vector_type(8))) __bf16 bf16x8;
typedef __attribute__((ext_vector_type(4))) float f32x4;

// ---------------------------------------------------------------------------
// LN1 + cast to bf16, emitting both normal and seq-flipped copies.
// One block per row.
// ---------------------------------------------------------------------------
__global__ __launch_bounds__(256) void ln1_cast(const float* __restrict__ x,
                                                const float* __restrict__ w,
                                                const float* __restrict__ b,
                                                bf16_t* __restrict__ xn_bf,
                                                bf16_t* __restrict__ xnr_bf) {
  int row = blockIdx.x;
  const float* xr = x + (size_t)row * DM;
  float s = 0.f, s2 = 0.f;
  for (int i = threadIdx.x; i < DM; i += 256) {
    float v = xr[i];
    s += v; s2 += v * v;
  }
  #pragma unroll
  for (int off = 32; off > 0; off >>= 1) {
    s  += __shfl_down(s, off);
    s2 += __shfl_down(s2, off);
  }
  __shared__ float ss[4], ss2[4];
  int wid = threadIdx.x >> 6;
  if ((threadIdx.x & 63) == 0) { ss[wid] = s; ss2[wid] = s2; }
  __syncthreads();
  if (threadIdx.x == 0) {
    float a = 0.f, a2 = 0.f;
    #pragma unroll
    for (int i = 0; i < 4; i++) { a += ss[i]; a2 += ss2[i]; }
    ss[0] = a; ss2[0] = a2;
  }
  __syncthreads();
  float mu  = ss[0] / DM;
  float var = ss2[0] / DM - mu * mu;
  float inv = rsqrtf(var + 1e-5f);
  int rf = (row & ~1023) + (1023 - (row & 1023));
  for (int i = threadIdx.x; i < DM; i += 256) {
    float v = (xr[i] - mu) * inv * w[i] + b[i];
    bf16_t bv = (bf16_t)v;
    xn_bf [(size_t)row * DM + i] = bv;
    xnr_bf[(size_t)rf  * DM + i] = bv;
  }
}

// ---------------------------------------------------------------------------
// fp32 -> bf16 with zero padding: src [N][K] -> dst [Npad][Kpad]
// ---------------------------------------------------------------------------
__global__ __launch_bounds__(256) void cast_pad(const float* __restrict__ src,
                                                bf16_t* __restrict__ dst,
                                                int N, int K, int Kpad) {
  int g = blockIdx.x * 256 + threadIdx.x;   // over Npad*Kpad (exact grid)
  int row = g / Kpad, col = g % Kpad;
  float v = (row < N && col < K) ? src[(size_t)row * K + col] : 0.f;
  dst[g] = (bf16_t)v;
}

// ---------------------------------------------------------------------------
// bf16 MFMA GEMM: C[M,N] = A[M,K] @ W[N,K]^T   (fp32 out, no epilogue)
// Tile 128x128xK, BK=32, 256 threads = 4 waves in 2x2, each wave 4x4 MFMAs.
// Grid: (N/128, M/128, SK). z-slice covers kChunk of K; if partStride>0
// each z writes to C + z*partStride (split-K partials).
// ---------------------------------------------------------------------------
__global__ __launch_bounds__(256) void gemm_bf16(
    const bf16_t* __restrict__ A, int lda,
    const bf16_t* __restrict__ W, int ldw,
    float* __restrict__ C, int ldc,
    int kChunk, long partStride) {
  __shared__ __align__(16) bf16_t As[128 * 32];
  __shared__ __align__(16) bf16_t Bs[128 * 32];
  int t = threadIdx.x;
  int n0 = blockIdx.x * 128;
  int m0 = blockIdx.y * 128;
  int z  = blockIdx.z;
  if (partStride) C += (size_t)z * partStride;
  int k0 = z * kChunk;

  int lane = t & 63;
  int w    = t >> 6;
  int wm = (w >> 1) * 64, wn = (w & 1) * 64;
  int quad = lane >> 4, l16 = lane & 15;

  f32x4 acc[4][4] = {};

  const bf16_t* Abase = A + (size_t)m0 * lda + k0;
  const bf16_t* Wbase = W + (size_t)n0 * ldw + k0;

  for (int kt = 0; kt < kChunk; kt += 32) {
    #pragma unroll
    for (int p = 0; p < 2; p++) {
      int ci  = p * 256 + t;         // 16B chunk id, 0..511
      int row = ci >> 2;             // 64B per row (32 bf16)
      int ko  = (ci & 3) * 8;        // element offset in k
      __builtin_amdgcn_global_load_lds(
          (const __attribute__((address_space(1))) void*)(Abase + (size_t)row * lda + kt + ko),
          (__attribute__((address_space(3))) void*)((char*)As + ci * 16), 16, 0, 0);
      __builtin_amdgcn_global_load_lds(
          (const __attribute__((address_space(1))) void*)(Wbase + (size_t)row * ldw + kt + ko),
          (__attribute__((address_space(3))) void*)((char*)Bs + ci * 16), 16, 0, 0);
    }
    __syncthreads();
    const bf16x8* Ap = (const bf16x8*)As;
    const bf16x8* Bp = (const bf16x8*)Bs;
    bf16x8 af[4], bfr[4];
    #pragma unroll
    for (int i = 0; i < 4; i++) af[i]  = Ap[(wm + i * 16 + l16) * 4 + quad];
    #pragma unroll
    for (int j = 0; j < 4; j++) bfr[j] = Bp[(wn + j * 16 + l16) * 4 + quad];
    #pragma unroll
    for (int i = 0; i < 4; i++)
      #pragma unroll
      for (int j = 0; j < 4; j++)
        acc[i][j] = __builtin_amdgcn_mfma_f32_16x16x32_bf16(af[i], bfr[j], acc[i][j], 0, 0, 0);
    __syncthreads();
  }

  #pragma unroll
  for (int i = 0; i < 4; i++) {
    int gm = m0 + wm + i * 16 + quad * 4;
    #pragma unroll
    for (int j = 0; j < 4; j++) {
      int gn = n0 + wn + j * 16 + l16;
      #pragma unroll
      for (int r = 0; r < 4; r++)
        C[(size_t)(gm + r) * ldc + gn] = acc[i][j][r];
    }
  }
}

// ---------------------------------------------------------------------------
// Causal depthwise conv (k=4) + bias + silu -> bf16.  xz [BL,2*DI], first half.
// ---------------------------------------------------------------------------
__global__ __launch_bounds__(256) void conv_silu(const float* __restrict__ xz,
                                                 const float* __restrict__ cw,
                                                 const float* __restrict__ cb,
                                                 bf16_t* __restrict__ out) {
  int g = blockIdx.x * 256 + threadIdx.x;          // BL*DI total
  int d = g % DI;
  int r = g / DI;
  int b = r >> 10, l = r & 1023;
  float v = cb[d];
  #pragma unroll
  for (int k = 0; k < DC; k++) {
    int li = l - (DC - 1) + k;
    if (li >= 0)
      v = fmaf(xz[((size_t)((b << 10) + li)) * (2 * DI) + d], cw[d * DC + k], v);
  }
  float s = v / (1.f + __expf(-v));                // silu
  out[(size_t)r * DI + d] = (bf16_t)s;
}

// ---------------------------------------------------------------------------
// Sum 8 split-K partials [8][2048][128] -> xdbl fp32 [2048][80]
// ---------------------------------------------------------------------------
__global__ __launch_bounds__(256) void reduce80(const float* __restrict__ part,
                                                float* __restrict__ xdbl) {
  int g = blockIdx.x * 256 + threadIdx.x;          // 2048*80
  int r = g / 80, c = g % 80;
  float s = 0.f;
  #pragma unroll
  for (int z = 0; z < 8; z++)
    s += part[((size_t)z * 2048 + r) * 128 + c];
  xdbl[g] = s;
}

// ---------------------------------------------------------------------------
// xdt_bf [2048][64] = bf16(xdbl[:, :48]) zero-padded
// ---------------------------------------------------------------------------
__global__ __launch_bounds__(256) void dt_prep(const float* __restrict__ xdbl,
                                               bf16_t* __restrict__ xdt_bf) {
  int g = blockIdx.x * 256 + threadIdx.x;          // 2048*64
  int r = g >> 6, c = g & 63;
  float v = (c < DTR) ? xdbl[(size_t)r * 80 + c] : 0.f;
  xdt_bf[g] = (bf16_t)v;
}

// ---------------------------------------------------------------------------
// dtb = softplus(dtb + dt_proj_b) in place
// ---------------------------------------------------------------------------
__global__ __launch_bounds__(256) void softplus_dt(float* __restrict__ dtb,
                                                   const float* __restrict__ db) {
  int g = blockIdx.x * 256 + threadIdx.x;          // 2048*1536
  int c = g % DI;
  float v = dtb[g] + db[c];
  dtb[g] = (v > 20.f) ? v : log1pf(expf(v));
}

// ---------------------------------------------------------------------------
// Scan pass A: per (b,d,chunk) local scan with h0=0.
// ---------------------------------------------------------------------------
__global__ __launch_bounds__(256) void scan_passA(const float* __restrict__ dt,
                                                  const bf16_t* __restrict__ xcc,
                                                  const float* __restrict__ xdbl,
                                                  const float* __restrict__ A_log,
                                                  float* __restrict__ P,
                                                  float* __restrict__ S) {
  int g = blockIdx.x * 256 + threadIdx.x;          // Bq*DI*NCH
  int d = g % DI;
  int rest = g / DI;
  int c = rest % NCH;
  int b = rest / NCH;
  float Av[DS], h[DS], Pr[DS];
  #pragma unroll
  for (int n = 0; n < DS; n++) {
    Av[n] = -expf(A_log[d * DS + n]);
    h[n] = 0.f; Pr[n] = 1.f;
  }
  for (int t = 0; t < CLEN; t++) {
    int l = c * CLEN + t;
    int r = (b << 10) + l;
    float dtv = dt[(size_t)r * DI + d];
    float xcv = (float)xcc[(size_t)r * DI + d];
    float dx = dtv * xcv;
    const float* Bp = xdbl + (size_t)r * 80 + DTR;
    #pragma unroll
    for (int n = 0; n < DS; n++) {
      float dA = __expf(dtv * Av[n]);
      h[n] = fmaf(dA, h[n], dx * Bp[n]);
      Pr[n] *= dA;
    }
  }
  size_t base = (((size_t)(b * DI + d)) * NCH + c) * DS;
  #pragma unroll
  for (int n = 0; n < DS; n++) { P[base + n] = Pr[n]; S[base + n] = h[n]; }
}

// ---------------------------------------------------------------------------
// Scan pass B: sequential scan over chunks; H[c] = carry INTO chunk c.
// ---------------------------------------------------------------------------
__global__ __launch_bounds__(256) void scan_passB(const float* __restrict__ P,
                                                  const float* __restrict__ S,
                                                  float* __restrict__ H) {
  int g = blockIdx.x * 256 + threadIdx.x;          // Bq*DI*DS
  int n = g & (DS - 1);
  int d = (g >> 4) % DI;
  int b = g / (DS * DI);
  size_t base = ((size_t)(b * DI + d)) * NCH * DS + n;
  float h = 0.f;
  for (int c = 0; c < NCH; c++) {
    size_t idx = base + (size_t)c * DS;
    H[idx] = h;
    h = fmaf(P[idx], h, S[idx]);
  }
}

// ---------------------------------------------------------------------------
// Scan pass C: replay chunk with carry-in; yact_bf = bf16((y+xc*D)*silu(z))
// ---------------------------------------------------------------------------
__global__ __launch_bounds__(256) void scan_passC(const float* __restrict__ dt,
                                                  const bf16_t* __restrict__ xcc,
                                                  const float* __restrict__ xdbl,
                                                  const float* __restrict__ A_log,
                                                  const float* __restrict__ H,
                                                  const float* __restrict__ Dvec,
                                                  const float* __restrict__ xz,
                                                  bf16_t* __restrict__ yact) {
  int g = blockIdx.x * 256 + threadIdx.x;
  int d = g % DI;
  int rest = g / DI;
  int c = rest % NCH;
  int b = rest / NCH;
  float Av[DS], h[DS];
  size_t base = (((size_t)(b * DI + d)) * NCH + c) * DS;
  #pragma unroll
  for (int n = 0; n < DS; n++) {
    Av[n] = -expf(A_log[d * DS + n]);
    h[n] = H[base + n];
  }
  float Dd = Dvec[d];
  for (int t = 0; t < CLEN; t++) {
    int l = c * CLEN + t;
    int r = (b << 10) + l;
    float dtv = dt[(size_t)r * DI + d];
    float xcv = (float)xcc[(size_t)r * DI + d];
    float dx = dtv * xcv;
    const float* Bp = xdbl + (size_t)r * 80 + DTR;
    const float* Cp = xdbl + (size_t)r * 80 + DTR + DS;
    float y = 0.f;
    #pragma unroll
    for (int n = 0; n < DS; n++) {
      float dA = __expf(dtv * Av[n]);
      h[n] = fmaf(dA, h[n], dx * Bp[n]);
      y = fmaf(h[n], Cp[n], y);
    }
    float z = xz[(size_t)r * (2 * DI) + DI + d];
    float sz = z / (1.f + __expf(-z));
    yact[(size_t)r * DI + d] = (bf16_t)((y + xcv * Dd) * sz);
  }
}

// ---------------------------------------------------------------------------
// t = part[0] + part[1]  (out_proj split-K reduce), [2048*768]
// ---------------------------------------------------------------------------
__global__ __launch_bounds__(256) void reduce2(const float* __restrict__ part,
                                               float* __restrict__ t) {
  int g = blockIdx.x * 256 + threadIdx.x;
  t[g] = part[g] + part[(size_t)2048 * 768 + g];
}

// ---------------------------------------------------------------------------
// x2 = x + t0 + flip(t1);  LN2;  xh_bf = bf16(LN2(x2)).  One block per row.
// ---------------------------------------------------------------------------
__global__ __launch_bounds__(256) void resid_ln2(const float* __restrict__ x,
                                                 const float* __restrict__ t0,
                                                 const float* __restrict__ t1,
                                                 const float* __restrict__ w,
                                                 const float* __restrict__ b,
                                                 float* __restrict__ x2,
                                                 bf16_t* __restrict__ xh_bf) {
  int row = blockIdx.x;
  int rf = (row & ~1023) + (1023 - (row & 1023));
  float v[3];
  float s = 0.f, s2 = 0.f;
  #pragma unroll
  for (int p = 0; p < 3; p++) {
    int i = p * 256 + threadIdx.x;
    float vv = x[(size_t)row * DM + i] + t0[(size_t)row * DM + i] + t1[(size_t)rf * DM + i];
    v[p] = vv;
    s += vv; s2 += vv * vv;
  }
  #pragma unroll
  for (int off = 32; off > 0; off >>= 1) {
    s  += __shfl_down(s, off);
    s2 += __shfl_down(s2, off);
  }
  __shared__ float ss[4], ss2[4];
  int wid = threadIdx.x >> 6;
  if ((threadIdx.x & 63) == 0) { ss[wid] = s; ss2[wid] = s2; }
  __syncthreads();
  if (threadIdx.x == 0) {
    float a = 0.f, a2 = 0.f;
    #pragma unroll
    for (int i = 0; i < 4; i++) { a += ss[i]; a2 += ss2[i]; }
    ss[0] = a; ss2[0] = a2;
  }
  __syncthreads();
  float mu  = ss[0] / DM;
  float var = ss2[0] / DM - mu * mu;
  float inv = rsqrtf(var + 1e-5f);
  #pragma unroll
  for (int p = 0; p < 3; p++) {
    int i = p * 256 + threadIdx.x;
    x2[(size_t)row * DM + i] = v[p];
    xh_bf[(size_t)row * DM + i] = (bf16_t)((v[p] - mu) * inv * w[i] + b[i]);
  }
}

// ---------------------------------------------------------------------------
// out = gelu(part0+part1 + fc_b) + x2
// ---------------------------------------------------------------------------
__global__ __launch_bounds__(256) void final_gelu(const float* __restrict__ part,
                                                  const float* __restrict__ fc_b,
                                                  const float* __restrict__ x2,
                                                  float* __restrict__ out) {
  int g = blockIdx.x * 256 + threadIdx.x;
  int c = g % DM;
  float v = part[g] + part[(size_t)2048 * 768 + g] + fc_b[c];
  float gl = 0.5f * v * (1.f + erff(v * 0.70710678118654752f));
  out[g] = gl + x2[g];
}

// ---------------------------------------------------------------------------
extern "C" void kernel_launch(void* const* d_in, const int* in_sizes, int n_in,
                              void* d_out, int out_size, void* d_ws, size_t ws_size,
                              hipStream_t stream) {
  const float* x     = (const float*)d_in[0];
  const float* ln1_w = (const float*)d_in[1];
  const float* ln1_b = (const float*)d_in[2];
  const float* ln2_w = (const float*)d_in[3];
  const float* ln2_b = (const float*)d_in[4];
  const float* fc_w  = (const float*)d_in[5];
  const float* fc_b  = (const float*)d_in[6];

  float* ws = (float*)d_ws;
  float* xz    = ws;                  // 6291456
  float* dtb   = xz   + 6291456;      // 3145728
  float* xdbl  = dtb  + 3145728;      //  163840
  float* Pb    = xdbl + 163840;       // 1572864
  float* Sb    = Pb   + 1572864;      // 1572864
  float* Hb    = Sb   + 1572864;      // 1572864
  float* part  = Pb;                  // alias: lifetime-disjoint with P/S
  float* t0    = Hb   + 1572864;      // 1572864
  float* t1    = t0   + 1572864;      // 1572864
  float* x2    = t1   + 1572864;      // 1572864
  bf16_t* bb     = (bf16_t*)(x2 + 1572864);
  bf16_t* xn_bf  = bb;                // 1572864
  bf16_t* xnr_bf = xn_bf  + 1572864;  // 1572864
  bf16_t* xcc_bf = xnr_bf + 1572864;  // 3145728
  bf16_t* xdt_bf = xcc_bf + 3145728;  //  131072
  bf16_t* yact_bf= xdt_bf + 131072;   // 3145728
  bf16_t* xh_bf  = yact_bf+ 3145728;  // 1572864
  bf16_t* w_in   = xh_bf  + 1572864;  // 2359296
  bf16_t* w_xp   = w_in   + 2359296;  //  196608 (padded 128x1536)
  bf16_t* w_dt   = w_xp   + 196608;   //   98304 (padded 1536x64)
  bf16_t* w_out  = w_dt   + 98304;    // 1179648
  bf16_t* w_fc   = w_out  + 1179648;  //  589824

  // LN1 -> bf16 (normal + flipped)
  ln1_cast<<<BL, 256, 0, stream>>>(x, ln1_w, ln1_b, xn_bf, xnr_bf);
  // fc weight once
  cast_pad<<<2304, 256, 0, stream>>>(fc_w, w_fc, DM, DM, DM);

  for (int dir = 0; dir < 2; dir++) {
    int pi = 7 + dir * 9;
    const float* in_proj_w  = (const float*)d_in[pi + 0];
    const float* conv_w     = (const float*)d_in[pi + 1];
    const float* conv_b     = (const float*)d_in[pi + 2];
    const float* x_proj_w   = (const float*)d_in[pi + 3];
    const float* dt_proj_w  = (const float*)d_in[pi + 4];
    const float* dt_proj_b  = (const float*)d_in[pi + 5];
    const float* A_log      = (const float*)d_in[pi + 6];
    const float* Dvec       = (const float*)d_in[pi + 7];
    const float* out_proj_w = (const float*)d_in[pi + 8];

    // weight casts
    cast_pad<<<9216, 256, 0, stream>>>(in_proj_w, w_in, 2 * DI, DM, DM);
    cast_pad<<<768,  256, 0, stream>>>(x_proj_w,  w_xp, DTR + 2 * DS, DI, DI);
    cast_pad<<<384,  256, 0, stream>>>(dt_proj_w, w_dt, DI, DTR, 64);
    cast_pad<<<4608, 256, 0, stream>>>(out_proj_w, w_out, DM, DI, DI);

    const bf16_t* Ain = dir ? xnr_bf : xn_bf;
    // xz = xn @ in_proj_w.T   [2048 x 3072], K=768
    gemm_bf16<<<dim3(24, 16, 1), 256, 0, stream>>>(Ain, DM, w_in, DM,
                                                   xz, 2 * DI, DM, 0);
    // conv + silu -> bf16
    conv_silu<<<(BL * DI) / 256, 256, 0, stream>>>(xz, conv_w, conv_b, xcc_bf);
    // x_dbl: split-K=8 partials then reduce  [2048 x 80], K=1536
    gemm_bf16<<<dim3(1, 16, 8), 256, 0, stream>>>(xcc_bf, DI, w_xp, DI,
                                                  part, 128, DI / 8, (long)2048 * 128);
    reduce80<<<640, 256, 0, stream>>>(part, xdbl);
    // dt raw = xdt @ dt_proj_w.T  [2048 x 1536], K=64(padded)
    dt_prep<<<512, 256, 0, stream>>>(xdbl, xdt_bf);
    gemm_bf16<<<dim3(12, 16, 1), 256, 0, stream>>>(xdt_bf, 64, w_dt, 64,
                                                   dtb, DI, 64, 0);
    softplus_dt<<<(BL * DI) / 256, 256, 0, stream>>>(dtb, dt_proj_b);
    // chunked selective scan
    scan_passA<<<(Bq * DI * NCH) / 256, 256, 0, stream>>>(dtb, xcc_bf, xdbl, A_log, Pb, Sb);
    scan_passB<<<(Bq * DI * DS) / 256, 256, 0, stream>>>(Pb, Sb, Hb);
    scan_passC<<<(Bq * DI * NCH) / 256, 256, 0, stream>>>(dtb, xcc_bf, xdbl, A_log, Hb,
                                                          Dvec, xz, yact_bf);
    // out_proj: split-K=2 then reduce  [2048 x 768], K=1536
    gemm_bf16<<<dim3(6, 16, 2), 256, 0, stream>>>(yact_bf, DI, w_out, DI,
                                                  part, DM, DI / 2, (long)2048 * 768);
    reduce2<<<6144, 256, 0, stream>>>(part, dir ? t1 : t0);
  }

  // x2 = x + t0 + flip(t1); LN2 -> xh_bf
  resid_ln2<<<BL, 256, 0, stream>>>(x, t0, t1, ln2_w, ln2_b, x2, xh_bf);
  // fc: split-K=2  [2048 x 768], K=768
  gemm_bf16<<<dim3(6, 16, 2), 256, 0, stream>>>(xh_bf, DM, w_fc, DM,
                                                part, DM, DM / 2, (long)2048 * 768);
  // out = gelu(fc + b) + x2
  final_gelu<<<6144, 256, 0, stream>>>(part, fc_b, x2, (float*)d_out);
}

// Round 3
// 479.055 us; speedup vs baseline: 2.7702x; 1.0596x over previous
//
#include <hip/hip_runtime.h>
#include <math.h>

// Problem constants
#define Bq 2
#define Lq 1024
#define DM 768
#define DI 1536
#define DS 16
#define DTR 48
#define DC 4
#define BL 2048          // B*L rows
#define NCH 128          // scan chunks
#define CLEN 8           // chunk length (NCH*CLEN == Lq)

typedef __bf16 bf16_t;
typedef __attribute__((ext_vector_type(8))) __bf16 bf16x8;
typedef __attribute__((ext_vector_type(4))) float f32x4;

// ---------------------------------------------------------------------------
// LN1 + cast to bf16, emitting both normal and seq-flipped copies.
// ---------------------------------------------------------------------------
__global__ __launch_bounds__(256) void ln1_cast(const float* __restrict__ x,
                                                const float* __restrict__ w,
                                                const float* __restrict__ b,
                                                bf16_t* __restrict__ xn_bf,
                                                bf16_t* __restrict__ xnr_bf) {
  int row = blockIdx.x;
  const float* xr = x + (size_t)row * DM;
  float s = 0.f, s2 = 0.f;
  for (int i = threadIdx.x; i < DM; i += 256) {
    float v = xr[i];
    s += v; s2 += v * v;
  }
  #pragma unroll
  for (int off = 32; off > 0; off >>= 1) {
    s  += __shfl_down(s, off);
    s2 += __shfl_down(s2, off);
  }
  __shared__ float ss[4], ss2[4];
  int wid = threadIdx.x >> 6;
  if ((threadIdx.x & 63) == 0) { ss[wid] = s; ss2[wid] = s2; }
  __syncthreads();
  if (threadIdx.x == 0) {
    float a = 0.f, a2 = 0.f;
    #pragma unroll
    for (int i = 0; i < 4; i++) { a += ss[i]; a2 += ss2[i]; }
    ss[0] = a; ss2[0] = a2;
  }
  __syncthreads();
  float mu  = ss[0] / DM;
  float var = ss2[0] / DM - mu * mu;
  float inv = rsqrtf(var + 1e-5f);
  int rf = (row & ~1023) + (1023 - (row & 1023));
  for (int i = threadIdx.x; i < DM; i += 256) {
    float v = (xr[i] - mu) * inv * w[i] + b[i];
    bf16_t bv = (bf16_t)v;
    xn_bf [(size_t)row * DM + i] = bv;
    xnr_bf[(size_t)rf  * DM + i] = bv;
  }
}

// ---------------------------------------------------------------------------
// fp32 -> bf16 with zero padding: src [N][K] -> dst [Npad][Kpad] (fc weight)
// ---------------------------------------------------------------------------
__global__ __launch_bounds__(256) void cast_pad(const float* __restrict__ src,
                                                bf16_t* __restrict__ dst,
                                                int N, int K, int Kpad) {
  int g = blockIdx.x * 256 + threadIdx.x;
  int row = g / Kpad, col = g % Kpad;
  float v = (row < N && col < K) ? src[(size_t)row * K + col] : 0.f;
  dst[g] = (bf16_t)v;
}

// ---------------------------------------------------------------------------
// Fused per-direction weight cast: in_proj, x_proj(pad rows to 128),
// dt_proj(pad cols 48->64), out_proj.  Exact grid 14976x256.
// ---------------------------------------------------------------------------
#define SEG0 (3072 * 768)
#define SEG1 (128 * 1536)
#define SEG2 (1536 * 64)
#define SEG3 (768 * 1536)
__global__ __launch_bounds__(256) void cast_weights(
    const float* __restrict__ in_proj_w, const float* __restrict__ x_proj_w,
    const float* __restrict__ dt_proj_w, const float* __restrict__ out_proj_w,
    bf16_t* __restrict__ w_in, bf16_t* __restrict__ w_xp,
    bf16_t* __restrict__ w_dt, bf16_t* __restrict__ w_out) {
  int g = blockIdx.x * 256 + threadIdx.x;
  if (g < SEG0) {
    w_in[g] = (bf16_t)in_proj_w[g];
    return;
  }
  g -= SEG0;
  if (g < SEG1) {
    int row = g / 1536;
    w_xp[g] = (row < 80) ? (bf16_t)x_proj_w[g] : (bf16_t)0.f;
    return;
  }
  g -= SEG1;
  if (g < SEG2) {
    int row = g >> 6, col = g & 63;
    w_dt[g] = (col < DTR) ? (bf16_t)dt_proj_w[row * DTR + col] : (bf16_t)0.f;
    return;
  }
  g -= SEG2;
  w_out[g] = (bf16_t)out_proj_w[g];
}

// ---------------------------------------------------------------------------
// bf16 MFMA GEMM: C[M,N] = A[M,K] @ W[N,K]^T   (fp32 out)
// Tile 128x128, BK=32, 256 threads = 4 waves 2x2, each wave 4x4 MFMAs.
// Grid: (N/128, M/128, SK); z covers kChunk of K, writes C + z*partStride.
// ---------------------------------------------------------------------------
__global__ __launch_bounds__(256) void gemm_bf16(
    const bf16_t* __restrict__ A, int lda,
    const bf16_t* __restrict__ W, int ldw,
    float* __restrict__ C, int ldc,
    int kChunk, long partStride) {
  __shared__ __align__(16) bf16_t As[128 * 32];
  __shared__ __align__(16) bf16_t Bs[128 * 32];
  int t = threadIdx.x;
  int n0 = blockIdx.x * 128;
  int m0 = blockIdx.y * 128;
  int z  = blockIdx.z;
  if (partStride) C += (size_t)z * partStride;
  int k0 = z * kChunk;

  int lane = t & 63;
  int w    = t >> 6;
  int wm = (w >> 1) * 64, wn = (w & 1) * 64;
  int quad = lane >> 4, l16 = lane & 15;

  f32x4 acc[4][4] = {};

  const bf16_t* Abase = A + (size_t)m0 * lda + k0;
  const bf16_t* Wbase = W + (size_t)n0 * ldw + k0;

  for (int kt = 0; kt < kChunk; kt += 32) {
    #pragma unroll
    for (int p = 0; p < 2; p++) {
      int ci  = p * 256 + t;         // 16B chunk id, 0..511
      int row = ci >> 2;             // 64B per row (32 bf16)
      int ko  = (ci & 3) * 8;
      __builtin_amdgcn_global_load_lds(
          (const __attribute__((address_space(1))) void*)(Abase + (size_t)row * lda + kt + ko),
          (__attribute__((address_space(3))) void*)((char*)As + ci * 16), 16, 0, 0);
      __builtin_amdgcn_global_load_lds(
          (const __attribute__((address_space(1))) void*)(Wbase + (size_t)row * ldw + kt + ko),
          (__attribute__((address_space(3))) void*)((char*)Bs + ci * 16), 16, 0, 0);
    }
    __syncthreads();
    const bf16x8* Ap = (const bf16x8*)As;
    const bf16x8* Bp = (const bf16x8*)Bs;
    bf16x8 af[4], bfr[4];
    #pragma unroll
    for (int i = 0; i < 4; i++) af[i]  = Ap[(wm + i * 16 + l16) * 4 + quad];
    #pragma unroll
    for (int j = 0; j < 4; j++) bfr[j] = Bp[(wn + j * 16 + l16) * 4 + quad];
    #pragma unroll
    for (int i = 0; i < 4; i++)
      #pragma unroll
      for (int j = 0; j < 4; j++)
        acc[i][j] = __builtin_amdgcn_mfma_f32_16x16x32_bf16(af[i], bfr[j], acc[i][j], 0, 0, 0);
    __syncthreads();
  }

  #pragma unroll
  for (int i = 0; i < 4; i++) {
    int gm = m0 + wm + i * 16 + quad * 4;
    #pragma unroll
    for (int j = 0; j < 4; j++) {
      int gn = n0 + wn + j * 16 + l16;
      #pragma unroll
      for (int r = 0; r < 4; r++)
        C[(size_t)(gm + r) * ldc + gn] = acc[i][j][r];
    }
  }
}

// ---------------------------------------------------------------------------
// Causal depthwise conv (k=4) + bias + silu -> bf16.
// ---------------------------------------------------------------------------
__global__ __launch_bounds__(256) void conv_silu(const float* __restrict__ xz,
                                                 const float* __restrict__ cw,
                                                 const float* __restrict__ cb,
                                                 bf16_t* __restrict__ out) {
  int g = blockIdx.x * 256 + threadIdx.x;
  int d = g % DI;
  int r = g / DI;
  int b = r >> 10, l = r & 1023;
  float v = cb[d];
  #pragma unroll
  for (int k = 0; k < DC; k++) {
    int li = l - (DC - 1) + k;
    if (li >= 0)
      v = fmaf(xz[((size_t)((b << 10) + li)) * (2 * DI) + d], cw[d * DC + k], v);
  }
  float s = v / (1.f + __expf(-v));
  out[(size_t)r * DI + d] = (bf16_t)s;
}

// ---------------------------------------------------------------------------
// Sum 16 split-K partials [16][2048][128] -> xdbl fp32 [2048][80],
// plus xdt_bf [2048][64] = bf16(xdbl[:, :48]) zero-padded.
// ---------------------------------------------------------------------------
__global__ __launch_bounds__(256) void reduce_xdbl(const float* __restrict__ part,
                                                   float* __restrict__ xdbl,
                                                   bf16_t* __restrict__ xdt_bf) {
  int g = blockIdx.x * 256 + threadIdx.x;          // 2048*80
  int r = g / 80, c = g % 80;
  float s = 0.f;
  #pragma unroll
  for (int z = 0; z < 16; z++)
    s += part[((size_t)z * 2048 + r) * 128 + c];
  xdbl[g] = s;
  if (c < 64)
    xdt_bf[(size_t)r * 64 + c] = (c < DTR) ? (bf16_t)s : (bf16_t)0.f;
}

__device__ __forceinline__ float softplus_f(float v) {
  return (v > 20.f) ? v : log1pf(__expf(v));
}

// ---------------------------------------------------------------------------
// Scan pass A: per (b,d,chunk) local scan with h0=0 (softplus fused).
// State layout: [b][chunk][d][n].  sumdt: [b][chunk][d].
// ---------------------------------------------------------------------------
__global__ __launch_bounds__(256) void scan_passA(const float* __restrict__ dtraw,
                                                  const float* __restrict__ dt_bias,
                                                  const bf16_t* __restrict__ xcc,
                                                  const float* __restrict__ xdbl,
                                                  const float* __restrict__ A_log,
                                                  float* __restrict__ S,
                                                  float* __restrict__ sumdt) {
  int g = blockIdx.x * 256 + threadIdx.x;          // Bq*NCH*DI
  int d = g % DI;
  int rest = g / DI;
  int c = rest % NCH;
  int b = rest / NCH;
  float Av[DS], h[DS];
  #pragma unroll
  for (int n = 0; n < DS; n++) {
    Av[n] = -__expf(A_log[d * DS + n]);
    h[n] = 0.f;
  }
  float bias = dt_bias[d];
  float sd = 0.f;
  for (int t = 0; t < CLEN; t++) {
    int r = (b << 10) + c * CLEN + t;
    float dtv = softplus_f(dtraw[(size_t)r * DI + d] + bias);
    sd += dtv;
    float xcv = (float)xcc[(size_t)r * DI + d];
    float dx = dtv * xcv;
    const float* Bp = xdbl + (size_t)r * 80 + DTR;
    #pragma unroll
    for (int n = 0; n < DS; n++)
      h[n] = fmaf(__expf(dtv * Av[n]), h[n], dx * Bp[n]);
  }
  size_t base = ((size_t)((b * NCH + c) * DI) + d) * DS;
  #pragma unroll
  for (int n = 0; n < DS; n++) S[base + n] = h[n];
  sumdt[(size_t)(b * NCH + c) * DI + d] = sd;
}

// ---------------------------------------------------------------------------
// Scan pass B: sequential scan over chunks; H[c] = carry INTO chunk c.
// Chunk decay reconstructed as exp(A * sumdt[chunk]).
// ---------------------------------------------------------------------------
__global__ __launch_bounds__(256) void scan_passB(const float* __restrict__ S,
                                                  const float* __restrict__ sumdt,
                                                  const float* __restrict__ A_log,
                                                  float* __restrict__ H) {
  int g = blockIdx.x * 256 + threadIdx.x;          // Bq*DI*DS
  int n = g & (DS - 1);
  int rest = g >> 4;
  int d = rest % DI;
  int b = rest / DI;
  float Av = -__expf(A_log[d * DS + n]);
  float h = 0.f;
  for (int c = 0; c < NCH; c++) {
    size_t ib = (size_t)(b * NCH + c) * DI + d;
    H[ib * DS + n] = h;
    h = fmaf(__expf(Av * sumdt[ib]), h, S[ib * DS + n]);
  }
}

// ---------------------------------------------------------------------------
// Scan pass C: replay chunk with carry-in; yact_bf = bf16((y+xc*D)*silu(z))
// ---------------------------------------------------------------------------
__global__ __launch_bounds__(256) void scan_passC(const float* __restrict__ dtraw,
                                                  const float* __restrict__ dt_bias,
                                                  const bf16_t* __restrict__ xcc,
                                                  const float* __restrict__ xdbl,
                                                  const float* __restrict__ A_log,
                                                  const float* __restrict__ H,
                                                  const float* __restrict__ Dvec,
                                                  const float* __restrict__ xz,
                                                  bf16_t* __restrict__ yact) {
  int g = blockIdx.x * 256 + threadIdx.x;
  int d = g % DI;
  int rest = g / DI;
  int c = rest % NCH;
  int b = rest / NCH;
  float Av[DS], h[DS];
  size_t base = ((size_t)((b * NCH + c) * DI) + d) * DS;
  #pragma unroll
  for (int n = 0; n < DS; n++) {
    Av[n] = -__expf(A_log[d * DS + n]);
    h[n] = H[base + n];
  }
  float bias = dt_bias[d];
  float Dd = Dvec[d];
  for (int t = 0; t < CLEN; t++) {
    int r = (b << 10) + c * CLEN + t;
    float dtv = softplus_f(dtraw[(size_t)r * DI + d] + bias);
    float xcv = (float)xcc[(size_t)r * DI + d];
    float dx = dtv * xcv;
    const float* Bp = xdbl + (size_t)r * 80 + DTR;
    const float* Cp = Bp + DS;
    float y = 0.f;
    #pragma unroll
    for (int n = 0; n < DS; n++) {
      h[n] = fmaf(__expf(dtv * Av[n]), h[n], dx * Bp[n]);
      y = fmaf(h[n], Cp[n], y);
    }
    float z = xz[(size_t)r * (2 * DI) + DI + d];
    float sz = z / (1.f + __expf(-z));
    yact[(size_t)r * DI + d] = (bf16_t)((y + xcv * Dd) * sz);
  }
}

// ---------------------------------------------------------------------------
// x2 = x + (p0a+p0b) + flip(p1a+p1b);  LN2 -> xh_bf.  One block per row.
// ---------------------------------------------------------------------------
__global__ __launch_bounds__(256) void resid_ln2(const float* __restrict__ x,
                                                 const float* __restrict__ part0,
                                                 const float* __restrict__ part1,
                                                 const float* __restrict__ w,
                                                 const float* __restrict__ b,
                                                 float* __restrict__ x2,
                                                 bf16_t* __restrict__ xh_bf) {
  const size_t PS = (size_t)2048 * 768;
  int row = blockIdx.x;
  int rf = (row & ~1023) + (1023 - (row & 1023));
  float v[3];
  float s = 0.f, s2 = 0.f;
  #pragma unroll
  for (int p = 0; p < 3; p++) {
    int i = p * 256 + threadIdx.x;
    size_t i0 = (size_t)row * DM + i, i1 = (size_t)rf * DM + i;
    float vv = x[i0] + part0[i0] + part0[PS + i0] + part1[i1] + part1[PS + i1];
    v[p] = vv;
    s += vv; s2 += vv * vv;
  }
  #pragma unroll
  for (int off = 32; off > 0; off >>= 1) {
    s  += __shfl_down(s, off);
    s2 += __shfl_down(s2, off);
  }
  __shared__ float ss[4], ss2[4];
  int wid = threadIdx.x >> 6;
  if ((threadIdx.x & 63) == 0) { ss[wid] = s; ss2[wid] = s2; }
  __syncthreads();
  if (threadIdx.x == 0) {
    float a = 0.f, a2 = 0.f;
    #pragma unroll
    for (int i = 0; i < 4; i++) { a += ss[i]; a2 += ss2[i]; }
    ss[0] = a; ss2[0] = a2;
  }
  __syncthreads();
  float mu  = ss[0] / DM;
  float var = ss2[0] / DM - mu * mu;
  float inv = rsqrtf(var + 1e-5f);
  #pragma unroll
  for (int p = 0; p < 3; p++) {
    int i = p * 256 + threadIdx.x;
    x2[(size_t)row * DM + i] = v[p];
    xh_bf[(size_t)row * DM + i] = (bf16_t)((v[p] - mu) * inv * w[i] + b[i]);
  }
}

// ---------------------------------------------------------------------------
// out = gelu(part0+part1 + fc_b) + x2
// ---------------------------------------------------------------------------
__global__ __launch_bounds__(256) void final_gelu(const float* __restrict__ part,
                                                  const float* __restrict__ fc_b,
                                                  const float* __restrict__ x2,
                                                  float* __restrict__ out) {
  int g = blockIdx.x * 256 + threadIdx.x;
  int c = g % DM;
  float v = part[g] + part[(size_t)2048 * 768 + g] + fc_b[c];
  float gl = 0.5f * v * (1.f + erff(v * 0.70710678118654752f));
  out[g] = gl + x2[g];
}

// ---------------------------------------------------------------------------
extern "C" void kernel_launch(void* const* d_in, const int* in_sizes, int n_in,
                              void* d_out, int out_size, void* d_ws, size_t ws_size,
                              hipStream_t stream) {
  const float* x     = (const float*)d_in[0];
  const float* ln1_w = (const float*)d_in[1];
  const float* ln1_b = (const float*)d_in[2];
  const float* ln2_w = (const float*)d_in[3];
  const float* ln2_b = (const float*)d_in[4];
  const float* fc_w  = (const float*)d_in[5];
  const float* fc_b  = (const float*)d_in[6];

  float* ws = (float*)d_ws;
  float* xz    = ws;                   // 6291456
  float* dtb   = xz    + 6291456;      // 3145728 (raw dt gemm out)
  float* xdbl  = dtb   + 3145728;      //  163840
  float* Sb    = xdbl  + 163840;       // 6291456
  float* Hb    = Sb    + 6291456;      // 6291456
  float* sumdt = Hb    + 6291456;      //  393216
  float* part0 = sumdt + 393216;       // 3145728 (out_proj dir0 partials)
  float* part1 = part0 + 3145728;      // 3145728 (out_proj dir1 partials)
  float* partx = part1 + 3145728;      // 4194304 (x_proj partials, 16 slices)
  float* x2    = partx + 4194304;      // 1572864
  float* partfc = part0;               // alias: part0 dead after resid_ln2
  bf16_t* bb     = (bf16_t*)(x2 + 1572864);
  bf16_t* xn_bf  = bb;                 // 1572864
  bf16_t* xnr_bf = xn_bf  + 1572864;   // 1572864
  bf16_t* xcc_bf = xnr_bf + 1572864;   // 3145728
  bf16_t* xdt_bf = xcc_bf + 3145728;   //  131072
  bf16_t* yact_bf= xdt_bf + 131072;    // 3145728
  bf16_t* xh_bf  = yact_bf+ 3145728;   // 1572864
  bf16_t* w_in   = xh_bf  + 1572864;   // 2359296
  bf16_t* w_xp   = w_in   + 2359296;   //  196608 (padded 128x1536)
  bf16_t* w_dt   = w_xp   + 196608;    //   98304 (padded 1536x64)
  bf16_t* w_out  = w_dt   + 98304;     // 1179648
  bf16_t* w_fc   = w_out  + 1179648;   //  589824

  ln1_cast<<<BL, 256, 0, stream>>>(x, ln1_w, ln1_b, xn_bf, xnr_bf);
  cast_pad<<<2304, 256, 0, stream>>>(fc_w, w_fc, DM, DM, DM);

  for (int dir = 0; dir < 2; dir++) {
    int pi = 7 + dir * 9;
    const float* in_proj_w  = (const float*)d_in[pi + 0];
    const float* conv_w     = (const float*)d_in[pi + 1];
    const float* conv_b     = (const float*)d_in[pi + 2];
    const float* x_proj_w   = (const float*)d_in[pi + 3];
    const float* dt_proj_w  = (const float*)d_in[pi + 4];
    const float* dt_proj_b  = (const float*)d_in[pi + 5];
    const float* A_log      = (const float*)d_in[pi + 6];
    const float* Dvec       = (const float*)d_in[pi + 7];
    const float* out_proj_w = (const float*)d_in[pi + 8];

    cast_weights<<<14976, 256, 0, stream>>>(in_proj_w, x_proj_w, dt_proj_w,
                                            out_proj_w, w_in, w_xp, w_dt, w_out);

    const bf16_t* Ain = dir ? xnr_bf : xn_bf;
    // xz = xn @ in_proj_w.T   [2048 x 3072], K=768
    gemm_bf16<<<dim3(24, 16, 1), 256, 0, stream>>>(Ain, DM, w_in, DM,
                                                   xz, 2 * DI, DM, 0);
    // conv + silu -> bf16
    conv_silu<<<(BL * DI) / 256, 256, 0, stream>>>(xz, conv_w, conv_b, xcc_bf);
    // x_dbl: split-K=16 partials then fused reduce (+dt_prep)
    gemm_bf16<<<dim3(1, 16, 16), 256, 0, stream>>>(xcc_bf, DI, w_xp, DI,
                                                   partx, 128, DI / 16, (long)2048 * 128);
    reduce_xdbl<<<640, 256, 0, stream>>>(partx, xdbl, xdt_bf);
    // dt raw = xdt @ dt_proj_w.T  [2048 x 1536], K=64(padded)
    gemm_bf16<<<dim3(12, 16, 1), 256, 0, stream>>>(xdt_bf, 64, w_dt, 64,
                                                   dtb, DI, 64, 0);
    // chunked selective scan (softplus fused)
    scan_passA<<<(Bq * DI * NCH) / 256, 256, 0, stream>>>(dtb, dt_proj_b, xcc_bf,
                                                          xdbl, A_log, Sb, sumdt);
    scan_passB<<<(Bq * DI * DS) / 256, 256, 0, stream>>>(Sb, sumdt, A_log, Hb);
    scan_passC<<<(Bq * DI * NCH) / 256, 256, 0, stream>>>(dtb, dt_proj_b, xcc_bf,
                                                          xdbl, A_log, Hb, Dvec,
                                                          xz, yact_bf);
    // out_proj: split-K=2 partials (reduced inside resid_ln2)
    gemm_bf16<<<dim3(6, 16, 2), 256, 0, stream>>>(yact_bf, DI, w_out, DI,
                                                  dir ? part1 : part0, DM,
                                                  DI / 2, (long)2048 * 768);
  }

  // x2 = x + p0 + flip(p1); LN2 -> xh_bf
  resid_ln2<<<BL, 256, 0, stream>>>(x, part0, part1, ln2_w, ln2_b, x2, xh_bf);
  // fc: split-K=2  [2048 x 768], K=768
  gemm_bf16<<<dim3(6, 16, 2), 256, 0, stream>>>(xh_bf, DM, w_fc, DM,
                                                partfc, DM, DM / 2, (long)2048 * 768);
  // out = gelu(fc + b) + x2
  final_gelu<<<6144, 256, 0, stream>>>(partfc, fc_b, x2, (float*)d_out);
}